// Round 10
// baseline (381.485 us; speedup 1.0000x reference)
//
#include <hip/hip_runtime.h>
#include <math.h>

#define DIMX   1024
#define NHEADS 16
#define HD     64
#define BATCH  4
#define SEQ    2048
#define NM     (BATCH * NHEADS * SEQ * HD)   // 8388608 elems per Q/K/V tensor

typedef unsigned short ushort_t;
typedef __attribute__((ext_vector_type(8))) short bf16x8;
typedef __attribute__((ext_vector_type(4))) short bf16x4;
typedef __attribute__((ext_vector_type(4))) float f32x4;

#define MFMA16(a, b, c) __builtin_amdgcn_mfma_f32_16x16x32_bf16(a, b, c, 0, 0, 0)

// K=16 bf16 MFMA (A,B = 4 bf16 each). gfx90a+ "_1k" builtin; asm fallback.
#if __has_builtin(__builtin_amdgcn_mfma_f32_16x16x16bf16_1k)
#define MFMA_PV(a, b, c) __builtin_amdgcn_mfma_f32_16x16x16bf16_1k(a, b, c, 0, 0, 0)
#else
static __device__ __forceinline__ f32x4 mfma_pv_asm(bf16x4 a, bf16x4 b, f32x4 c) {
    asm("v_mfma_f32_16x16x16_bf16 %0, %1, %2, %0" : "+v"(c) : "v"(a), "v"(b));
    return c;
}
#define MFMA_PV(a, b, c) mfma_pv_asm(a, b, c)
#endif

// round-to-nearest-even fp32 -> bf16 bits
__device__ __forceinline__ ushort_t f2bf(float x) {
    unsigned u = __float_as_uint(x);
    u += 0x7fffu + ((u >> 16) & 1u);
    return (ushort_t)(u >> 16);
}
__device__ __forceinline__ float bf2f(ushort_t h) {
    return __uint_as_float(((unsigned)h) << 16);
}

// pack two fp32 -> two TRUNCATED bf16 in one dword (lo in low half).
__device__ __forceinline__ unsigned pack_bf16_trunc(float lo, float hi) {
#if __has_builtin(__builtin_amdgcn_perm)
    return __builtin_amdgcn_perm(__float_as_uint(hi), __float_as_uint(lo), 0x07060302u);
#else
    return (__float_as_uint(lo) >> 16) | (__float_as_uint(hi) & 0xFFFF0000u);
#endif
}
__device__ __forceinline__ float trunc_bf(float x) {
    return __uint_as_float(__float_as_uint(x) & 0xFFFF0000u);
}

// raw v_exp_f32 (no ocml edge-case wrapper) — guarded
__device__ __forceinline__ float fast_exp2(float x) {
#if __has_builtin(__builtin_amdgcn_exp2f)
    return __builtin_amdgcn_exp2f(x);
#else
    return exp2f(x);
#endif
}

// async global->LDS, 16B per lane; LDS base wave-uniform (HW adds lane*16)
#define GLOAD_LDS16(g, l) \
    __builtin_amdgcn_global_load_lds((const __attribute__((address_space(1))) unsigned int*)(g), \
                                     (__attribute__((address_space(3))) unsigned int*)(l), 16, 0, 0)

// ---------------------------------------------------------------------------
// convert_x: split x fp32 -> Xhi, Xlo bf16.  (unchanged)
// ---------------------------------------------------------------------------
__global__ __launch_bounds__(256) void convert_x(
    const float* __restrict__ x, ushort_t* __restrict__ Xh, ushort_t* __restrict__ Xl)
{
    int i = blockIdx.x * 256 + threadIdx.x;
    #pragma unroll
    for (int t = 0; t < 4; t++) {
        int idx = t * 524288 + i;
        f32x4 v = ((const f32x4*)x)[idx];
        ushort4 hi, lo;
        hi.x = f2bf(v[0]); lo.x = f2bf(v[0] - bf2f(hi.x));
        hi.y = f2bf(v[1]); lo.y = f2bf(v[1] - bf2f(hi.y));
        hi.z = f2bf(v[2]); lo.z = f2bf(v[2] - bf2f(hi.z));
        hi.w = f2bf(v[3]); lo.w = f2bf(v[3] - bf2f(hi.w));
        ((ushort4*)Xh)[idx] = hi;
        ((ushort4*)Xl)[idx] = lo;
    }
}

// ---------------------------------------------------------------------------
// convert_w: transpose w[n][d][e] -> Wt[e'][d], split hi/lo bf16. (unchanged)
// ---------------------------------------------------------------------------
__global__ __launch_bounds__(256) void convert_w(
    const float* __restrict__ wk, const float* __restrict__ wq, const float* __restrict__ wv,
    ushort_t* __restrict__ Bqh, ushort_t* __restrict__ Bql, ushort_t* __restrict__ Bvh)
{
    __shared__ float Ts[64][65];
    const int bid = blockIdx.x;
    const int mat = bid >> 8;
    const int rem = bid & 255;
    const int n  = rem >> 4;
    const int dt = rem & 15;
    const float* w = (mat == 0) ? wq : (mat == 1) ? wk : wv;
    const int tid = threadIdx.x;

    #pragma unroll
    for (int t = 0; t < 16; t++) {
        int i = tid + t * 256;
        int r = i >> 6, e = i & 63;
        Ts[r][e] = w[((size_t)n * 1024 + dt * 64 + r) * 64 + e];
    }
    __syncthreads();
    #pragma unroll
    for (int t = 0; t < 16; t++) {
        int i = tid + t * 256;
        int e = i >> 6, r = i & 63;
        float v = Ts[r][e];
        ushort_t hi = f2bf(v);
        size_t o = (size_t)(n * 64 + e) * 1024 + dt * 64 + r;
        if (mat < 2) {
            Bqh[(size_t)mat * 1048576 + o] = hi;
            Bql[(size_t)mat * 1048576 + o] = f2bf(v - bf2f(hi));
        } else {
            Bvh[o] = hi;
        }
    }
}

// ---------------------------------------------------------------------------
// proj_qk: 3-pass split-bf16 MFMA GEMM. (unchanged)
// ---------------------------------------------------------------------------
__global__ __launch_bounds__(256) void proj_qk(
    const ushort_t* __restrict__ Xh, const ushort_t* __restrict__ Xl,
    const ushort_t* __restrict__ Bh, const ushort_t* __restrict__ Bl,
    float* __restrict__ Qf, ushort_t* __restrict__ Khi, ushort_t* __restrict__ Klo)
{
    __shared__ __align__(16) ushort_t Ah[128 * 64];
    __shared__ __align__(16) ushort_t Al[128 * 64];
    __shared__ __align__(16) ushort_t Bhs[128 * 64];
    __shared__ __align__(16) ushort_t Bls[128 * 64];

    const int mt = blockIdx.x, nt = blockIdx.y;
    const int tid = threadIdx.x;
    const int w = tid >> 6, lane = tid & 63, col = lane & 15, quad = lane >> 4;
    const int wm = w & 1, wn = w >> 1;

    f32x4 acc[4][4] = {};

    for (int kc = 0; kc < 1024; kc += 64) {
        __syncthreads();
        #pragma unroll
        for (int i = 0; i < 4; i++) {
            int s = (w * 4 + i) * 64 + lane;
            int r = s >> 3, j = s & 7, g = j ^ (r & 7);
            size_t aoff = (size_t)(mt * 128 + r) * 1024 + kc + g * 8;
            size_t boff = (size_t)(nt * 128 + r) * 1024 + kc + g * 8;
            GLOAD_LDS16(Xh + aoff, Ah  + (size_t)(w * 4 + i) * 512);
            GLOAD_LDS16(Xl + aoff, Al  + (size_t)(w * 4 + i) * 512);
            GLOAD_LDS16(Bh + boff, Bhs + (size_t)(w * 4 + i) * 512);
            GLOAD_LDS16(Bl + boff, Bls + (size_t)(w * 4 + i) * 512);
        }
        __syncthreads();
        #pragma unroll
        for (int kk = 0; kk < 2; kk++) {
            bf16x8 a_h[4], a_l[4], b_h[4], b_l[4];
            const int gi = kk * 4 + quad;
            #pragma unroll
            for (int t = 0; t < 4; t++) {
                int rA = wm * 64 + t * 16 + col;
                int jA = gi ^ (rA & 7);
                a_h[t] = *(const bf16x8*)&Ah[(rA * 8 + jA) * 8];
                a_l[t] = *(const bf16x8*)&Al[(rA * 8 + jA) * 8];
                int rB = wn * 64 + t * 16 + col;
                int jB = gi ^ (rB & 7);
                b_h[t] = *(const bf16x8*)&Bhs[(rB * 8 + jB) * 8];
                b_l[t] = *(const bf16x8*)&Bls[(rB * 8 + jB) * 8];
            }
            #pragma unroll
            for (int t = 0; t < 4; t++)
                #pragma unroll
                for (int u = 0; u < 4; u++) {
                    acc[t][u] = MFMA16(a_h[t], b_h[u], acc[t][u]);
                    acc[t][u] = MFMA16(a_l[t], b_h[u], acc[t][u]);
                    acc[t][u] = MFMA16(a_h[t], b_l[u], acc[t][u]);
                }
        }
    }

    const bool isQ = (nt < 8);
    #pragma unroll
    for (int t = 0; t < 4; t++) {
        #pragma unroll
        for (int u = 0; u < 4; u++) {
            int np = nt * 128 + wn * 64 + u * 16 + col;
            int head = (np >> 6) & 15, e = np & 63;
            #pragma unroll
            for (int rr = 0; rr < 4; rr++) {
                int mm = mt * 128 + wm * 64 + t * 16 + quad * 4 + rr;
                int bi = mm >> 11, l = mm & 2047;
                size_t base = (((size_t)bi * NHEADS + head) * SEQ + l) * HD + e;
                float v = acc[t][u][rr];
                if (isQ) {
                    Qf[base] = v;
                } else {
                    ushort_t hi = f2bf(v);
                    Khi[base] = hi;
                    Klo[base] = f2bf(v - bf2f(hi));
                }
            }
        }
    }
}

// ---------------------------------------------------------------------------
// proj_v: 1-pass bf16, operand-swapped for transposed-V output. (unchanged)
// ---------------------------------------------------------------------------
__global__ __launch_bounds__(256) void proj_v(
    const ushort_t* __restrict__ Wvh, const ushort_t* __restrict__ Xh,
    ushort_t* __restrict__ Vt)
{
    __shared__ __align__(16) ushort_t Ah[128 * 64];
    __shared__ __align__(16) ushort_t Bhs[128 * 64];

    const int mt = blockIdx.x, nt = blockIdx.y;
    const int tid = threadIdx.x;
    const int w = tid >> 6, lane = tid & 63, col = lane & 15, quad = lane >> 4;
    const int wm = w & 1, wn = w >> 1;

    f32x4 acc[4][4] = {};

    for (int kc = 0; kc < 1024; kc += 64) {
        __syncthreads();
        #pragma unroll
        for (int i = 0; i < 4; i++) {
            int s = (w * 4 + i) * 64 + lane;
            int r = s >> 3, j = s & 7, g = j ^ (r & 7);
            size_t aoff = (size_t)(mt * 128 + r) * 1024 + kc + g * 8;
            size_t boff = (size_t)(nt * 128 + r) * 1024 + kc + g * 8;
            GLOAD_LDS16(Wvh + aoff, Ah  + (size_t)(w * 4 + i) * 512);
            GLOAD_LDS16(Xh  + boff, Bhs + (size_t)(w * 4 + i) * 512);
        }
        __syncthreads();
        #pragma unroll
        for (int kk = 0; kk < 2; kk++) {
            bf16x8 a_h[4], b_h[4];
            const int gi = kk * 4 + quad;
            #pragma unroll
            for (int t = 0; t < 4; t++) {
                int rA = wm * 64 + t * 16 + col;
                a_h[t] = *(const bf16x8*)&Ah[(rA * 8 + (gi ^ (rA & 7))) * 8];
                int rB = wn * 64 + t * 16 + col;
                b_h[t] = *(const bf16x8*)&Bhs[(rB * 8 + (gi ^ (rB & 7))) * 8];
            }
            #pragma unroll
            for (int t = 0; t < 4; t++)
                #pragma unroll
                for (int u = 0; u < 4; u++)
                    acc[t][u] = MFMA16(a_h[t], b_h[u], acc[t][u]);
        }
    }

    #pragma unroll
    for (int t = 0; t < 4; t++) {
        #pragma unroll
        for (int rr = 0; rr < 4; rr++) {
            int ep = mt * 128 + wm * 64 + t * 16 + quad * 4 + rr;
            int head = ep >> 6, e = ep & 63;
            #pragma unroll
            for (int u = 0; u < 4; u++) {
                int lg = nt * 128 + wn * 64 + u * 16 + col;
                int bi = lg >> 11, l = lg & 2047;
                Vt[(((size_t)bi * NHEADS + head) * HD + e) * SEQ + l] = f2bf(acc[t][u][rr]);
            }
        }
    }
}

// ---------------------------------------------------------------------------
// Flash attention, operand-swapped (r8 m=4 structure) + round-10 change:
// DOUBLE-BUFFERED K/V staging with ONE barrier per chunk. stage(ch+1) is
// issued right after the barrier, so its VMEM latency hides behind
// compute(ch) instead of being exposed between two barriers, and waves can
// drift phases within a chunk (MFMA of one wave overlaps VALU of another).
// Barrier safety: barrier(ch) orders compute(ch-1) reads of buf[!cur]
// before stage(ch+1) writes of buf[!cur]; compiler's vmcnt drain before
// s_barrier guarantees buf[cur] staging landed.
// ---------------------------------------------------------------------------
__global__ __launch_bounds__(256, 2) void attn_mfma_kernel(
    const float* __restrict__ Qf, const ushort_t* __restrict__ Khi,
    const ushort_t* __restrict__ Klo, const ushort_t* __restrict__ Vt,
    float* __restrict__ out)
{
    __shared__ __align__(16) ushort_t Khs[2][64 * 64];
    __shared__ __align__(16) ushort_t Kls[2][64 * 64];
    __shared__ __align__(16) ushort_t Vts[2][64 * 64];

    const int qt  = blockIdx.x;       // 0..7 (256 q-rows per block)
    const int bn  = blockIdx.y;       // 0..63
    const int tid = threadIdx.x;
    const int w    = tid >> 6;
    const int lane = tid & 63;
    const int col  = lane & 15;
    const int quad = lane >> 4;

    const ushort_t* Kh_g = Khi + (size_t)bn * SEQ * HD;
    const ushort_t* Kl_g = Klo + (size_t)bn * SEQ * HD;
    const ushort_t* Vt_g = Vt  + (size_t)bn * HD * SEQ;

    // staging geometry (same swizzle as r8): this wave's 2 granule-slices
    const int G0   = (w * 2 + 0) * 64 + lane;
    const int G1   = (w * 2 + 1) * 64 + lane;
    const int key0 = G0 >> 3, blk0 = (G0 & 7) ^ (key0 & 7);
    const int key1 = G1 >> 3, blk1 = (G1 & 7) ^ (key1 & 7);

    // ---- Q fragments (B operand: n=lane&15=qrow, k=quad*8+j=e), scaled by
    //      log2e/sqrt(64), split hi/lo.
    union { bf16x8 v; short s[8]; } qh[4][2], ql[4][2];
    #pragma unroll
    for (int m = 0; m < 4; m++) {
        const int qrow = qt * 256 + w * 64 + m * 16 + col;
        const float* qp = Qf + ((size_t)bn * SEQ + qrow) * HD;
        #pragma unroll
        for (int ks = 0; ks < 2; ks++) {
            float qv[8];
            f32x4 a = *(const f32x4*)(qp + ks * 32 + quad * 8);
            f32x4 b = *(const f32x4*)(qp + ks * 32 + quad * 8 + 4);
            qv[0]=a[0]; qv[1]=a[1]; qv[2]=a[2]; qv[3]=a[3];
            qv[4]=b[0]; qv[5]=b[1]; qv[6]=b[2]; qv[7]=b[3];
            #pragma unroll
            for (int j = 0; j < 8; j++) {
                float xsc = qv[j] * (0.125f * 1.44269504088896f);   // log2e/sqrt(64)
                ushort_t hi = f2bf(xsc);
                ushort_t lo = f2bf(xsc - bf2f(hi));
                qh[m][ks].s[j] = (short)hi;
                ql[m][ks].s[j] = (short)lo;
            }
        }
    }

    f32x4 O[4][4] = {};                                   // O^T: [m][e-tile]
    float m_i[4] = {-1e30f, -1e30f, -1e30f, -1e30f};      // per-lane (qrow=col)
    float L[4]   = {0.f, 0.f, 0.f, 0.f};                  // per-lane partial denom

    // ---- prologue: stage chunk 0 into buffer 0
    {
        size_t k0 = (size_t)key0 * HD + blk0 * 8;
        size_t k1 = (size_t)key1 * HD + blk1 * 8;
        size_t v0 = (size_t)key0 * SEQ + blk0 * 8;
        size_t v1 = (size_t)key1 * SEQ + blk1 * 8;
        GLOAD_LDS16(Kh_g + k0, &Khs[0][(w * 2 + 0) * 512]);
        GLOAD_LDS16(Kh_g + k1, &Khs[0][(w * 2 + 1) * 512]);
        GLOAD_LDS16(Kl_g + k0, &Kls[0][(w * 2 + 0) * 512]);
        GLOAD_LDS16(Kl_g + k1, &Kls[0][(w * 2 + 1) * 512]);
        GLOAD_LDS16(Vt_g + v0, &Vts[0][(w * 2 + 0) * 512]);
        GLOAD_LDS16(Vt_g + v1, &Vts[0][(w * 2 + 1) * 512]);
    }

    for (int ch = 0; ch < 32; ch++) {
        const int cur = ch & 1;
        __syncthreads();   // buf[cur] staged & visible; compute(ch-1) on buf[!cur] done

        // ---- stage next chunk into the other buffer (hides behind compute)
        if (ch + 1 < 32) {
            const int nxt = cur ^ 1;
            size_t k0 = (size_t)((ch + 1) * 64 + key0) * HD + blk0 * 8;
            size_t k1 = (size_t)((ch + 1) * 64 + key1) * HD + blk1 * 8;
            size_t v0 = (size_t)key0 * SEQ + (ch + 1) * 64 + blk0 * 8;
            size_t v1 = (size_t)key1 * SEQ + (ch + 1) * 64 + blk1 * 8;
            GLOAD_LDS16(Kh_g + k0, &Khs[nxt][(w * 2 + 0) * 512]);
            GLOAD_LDS16(Kh_g + k1, &Khs[nxt][(w * 2 + 1) * 512]);
            GLOAD_LDS16(Kl_g + k0, &Kls[nxt][(w * 2 + 0) * 512]);
            GLOAD_LDS16(Kl_g + k1, &Kls[nxt][(w * 2 + 1) * 512]);
            GLOAD_LDS16(Vt_g + v0, &Vts[nxt][(w * 2 + 0) * 512]);
            GLOAD_LDS16(Vt_g + v1, &Vts[nxt][(w * 2 + 1) * 512]);
        }

        // ---- S^T = K Q^T (3-pass split): K frags read once, reused over m
        f32x4 St[4][4] = {};                              // [m][key-tile]
        #pragma unroll
        for (int ks = 0; ks < 2; ks++) {
            #pragma unroll
            for (int t = 0; t < 4; t++) {
                int key = t * 16 + col;
                int g = key * 8 + ((ks * 4 + quad) ^ (key & 7));
                bf16x8 kh = *(const bf16x8*)&Khs[cur][g * 8];
                bf16x8 kl = *(const bf16x8*)&Kls[cur][g * 8];
                #pragma unroll
                for (int m = 0; m < 4; m++) {
                    St[m][t] = MFMA16(kh, qh[m][ks].v, St[m][t]);
                    St[m][t] = MFMA16(kh, ql[m][ks].v, St[m][t]);
                    St[m][t] = MFMA16(kl, qh[m][ks].v, St[m][t]);
                }
            }
        }

        // ---- V^T A-fragments (m=lane&15=e, k=quad*4+j=key): b64 reads
        bf16x4 vfrag[4][4];                               // [e-tile][key-tile]
        #pragma unroll
        for (int u = 0; u < 4; u++) {
            int rowbase = (u * 16 + col) * 64;
            #pragma unroll
            for (int t = 0; t < 4; t++) {
                int g = (t * 2 + (quad >> 1)) ^ (col & 7);
                vfrag[u][t] = *(const bf16x4*)&Vts[cur][rowbase + g * 8 + (quad & 1) * 4];
            }
        }

        // ---- per-m: softmax (scalar per-lane state) + PV from registers
        #pragma unroll
        for (int m = 0; m < 4; m++) {
            float mx = St[m][0][0];
            #pragma unroll
            for (int t = 0; t < 4; t++)
                #pragma unroll
                for (int r = 0; r < 4; r++) mx = fmaxf(mx, St[m][t][r]);
            mx = fmaxf(mx, __shfl_xor(mx, 16));
            mx = fmaxf(mx, __shfl_xor(mx, 32));
            float mnew = fmaxf(m_i[m], mx);
            float al   = fast_exp2(m_i[m] - mnew);
            m_i[m] = mnew;

            float psum = 0.f;
            bf16x4 pf[4];                                 // P^T B-frags per key-tile
            #pragma unroll
            for (int t = 0; t < 4; t++) {
                float p0 = fast_exp2(St[m][t][0] - mnew);
                float p1 = fast_exp2(St[m][t][1] - mnew);
                float p2 = fast_exp2(St[m][t][2] - mnew);
                float p3 = fast_exp2(St[m][t][3] - mnew);
                psum += trunc_bf(p0) + trunc_bf(p1) + trunc_bf(p2) + trunc_bf(p3);
                union { unsigned u[2]; bf16x4 v; } pk;
                pk.u[0] = pack_bf16_trunc(p0, p1);
                pk.u[1] = pack_bf16_trunc(p2, p3);
                pf[t] = pk.v;
            }
            L[m] = L[m] * al + psum;                      // per-lane partial; al row-uniform
            #pragma unroll
            for (int u = 0; u < 4; u++) {
                O[m][u][0] *= al; O[m][u][1] *= al;
                O[m][u][2] *= al; O[m][u][3] *= al;
            }
            #pragma unroll
            for (int t = 0; t < 4; t++)
                #pragma unroll
                for (int u = 0; u < 4; u++)
                    O[m][u] = MFMA_PV(vfrag[u][t], pf[t], O[m][u]);
        }
    }

    // ---- epilogue: finish L across quads (2 shuffles), write float4 along e
    const int b = bn >> 4, n = bn & 15;
    #pragma unroll
    for (int m = 0; m < 4; m++) {
        float Lr = L[m];
        Lr += __shfl_xor(Lr, 16);
        Lr += __shfl_xor(Lr, 32);
        float inv = 1.0f / Lr;
        int l = qt * 256 + w * 64 + m * 16 + col;
        size_t base = ((size_t)(b * SEQ + l)) * (NHEADS * HD) + n * HD;
        #pragma unroll
        for (int u = 0; u < 4; u++) {
            f32x4 o;
            o[0] = O[m][u][0] * inv; o[1] = O[m][u][1] * inv;
            o[2] = O[m][u][2] * inv; o[3] = O[m][u][3] * inv;
            *(f32x4*)&out[base + u * 16 + quad * 4] = o;
        }
    }
}

// ---------------------------------------------------------------------------
extern "C" void kernel_launch(void* const* d_in, const int* in_sizes, int n_in,
                              void* d_out, int out_size, void* d_ws, size_t ws_size,
                              hipStream_t stream) {
    const float* x  = (const float*)d_in[0];
    const float* wk = (const float*)d_in[1];
    const float* wq = (const float*)d_in[2];
    const float* wv = (const float*)d_in[3];
    float* out = (float*)d_out;

    // ws layout (111 MB): Xh | Xl (aliased by Vt after proj_qk) | Bqh | Bql | Bvh | Qf | Khi | Klo
    ushort_t* Xh  = (ushort_t*)d_ws;
    ushort_t* Xl  = Xh + NM;
    ushort_t* Vt  = Xl;                      // alias: Xl dead once proj_qk finishes
    ushort_t* Bqh = Xl + NM;                 // [2048][1024]
    ushort_t* Bql = Bqh + 2097152;
    ushort_t* Bvh = Bql + 2097152;           // [1024][1024]
    float*    Qf  = (float*)(Bvh + 1048576);
    ushort_t* Khi = (ushort_t*)(Qf + NM);
    ushort_t* Klo = Khi + NM;

    convert_x<<<2048, 256, 0, stream>>>(x, Xh, Xl);
    convert_w<<<768, 256, 0, stream>>>(wk, wq, wv, Bqh, Bql, Bvh);
    proj_qk<<<dim3(64, 16), 256, 0, stream>>>(Xh, Xl, Bqh, Bql, Qf, Khi, Klo);
    proj_v<<<dim3(8, 64), 256, 0, stream>>>(Bvh, Xh, Vt);
    attn_mfma_kernel<<<dim3(8, 64), 256, 0, stream>>>(Qf, Khi, Klo, Vt, out);
}